// Round 2
// baseline (898.686 us; speedup 1.0000x reference)
//
#include <hip/hip_runtime.h>

#define DD 128
#define KSPLIT 8
#define BM 64
#define BK 64
#define K3R 32

typedef float f4 __attribute__((ext_vector_type(4)));
typedef _Float16 h4 __attribute__((ext_vector_type(4)));
typedef _Float16 h8 __attribute__((ext_vector_type(8)));
typedef unsigned int u32x4 __attribute__((ext_vector_type(4)));

// ---------------- K1: LayerNorm + gumbel gate + compaction ----------------
__global__ __launch_bounds__(256) void k1_ln_gate(
    const float* __restrict__ x, const float* __restrict__ u,
    const float* __restrict__ Wn, const float* __restrict__ bn,
    const float* __restrict__ g_in, const float* __restrict__ b_in,
    float* __restrict__ x_norm, float* __restrict__ gatef,
    int* __restrict__ rows_sel, int* __restrict__ cnt, int N) {
  int wave = threadIdx.x >> 6, lane = threadIdx.x & 63;
  int row = blockIdx.x * 4 + wave;
  if (row >= N) return;
  int d0 = lane, d1 = lane + 64;
  float x0 = x[(size_t)row * DD + d0];
  float x1 = x[(size_t)row * DD + d1];
  float s = x0 + x1;
#pragma unroll
  for (int off = 32; off; off >>= 1) s += __shfl_xor(s, off, 64);
  float mean = s * (1.0f / 128.0f);
  float dx0 = x0 - mean, dx1 = x1 - mean;
  float v = dx0 * dx0 + dx1 * dx1;
#pragma unroll
  for (int off = 32; off; off >>= 1) v += __shfl_xor(v, off, 64);
  float inv = 1.0f / sqrtf(v * (1.0f / 128.0f) + 1e-5f);
  float xn0 = dx0 * inv * g_in[d0] + b_in[d0];
  float xn1 = dx1 * inv * g_in[d1] + b_in[d1];
  x_norm[(size_t)row * DD + d0] = xn0;
  x_norm[(size_t)row * DD + d1] = xn1;
  float l0 = xn0 * Wn[2 * d0] + xn1 * Wn[2 * d1];
  float l1 = xn0 * Wn[2 * d0 + 1] + xn1 * Wn[2 * d1 + 1];
#pragma unroll
  for (int off = 32; off; off >>= 1) {
    l0 += __shfl_xor(l0, off, 64);
    l1 += __shfl_xor(l1, off, 64);
  }
  float u0 = u[2 * row], u1 = u[2 * row + 1];
  float g0 = -logf(-logf(fminf(fmaxf(u0, 1e-10f), 1.0f)) + 1e-10f);
  float g1 = -logf(-logf(fminf(fmaxf(u1, 1e-10f), 1.0f)) + 1e-10f);
  float z0 = l0 + bn[0] + g0;
  float z1 = l1 + bn[1] + g1;
  bool gate = (z1 > z0);
  if (lane == 0) {
    gatef[row] = gate ? 1.0f : 0.0f;
    if (gate) {
      int p = atomicAdd(cnt, 1);
      rows_sel[p] = row;
    }
  }
}

// ---------------- K1b: xg16T[d][n] = gate[n]*x_norm[n][d] in f16 (tiled transpose) ----
__global__ __launch_bounds__(256) void k1b_transpose(
    const float* __restrict__ x_norm, const float* __restrict__ gatef,
    _Float16* __restrict__ xg16T, int N) {
  __shared__ float tile[64][65];
  const int n0 = blockIdx.x * 64;
  const int d0 = blockIdx.y * 64;
  const int t = threadIdx.x;
  {
    const int c4 = (t & 15) * 4, r0 = t >> 4;
#pragma unroll
    for (int uu = 0; uu < 4; ++uu) {
      int r = r0 + 16 * uu;
      float gv = gatef[n0 + r];
      f4 v = *(const f4*)(x_norm + (size_t)(n0 + r) * DD + d0 + c4);
#pragma unroll
      for (int j = 0; j < 4; ++j) tile[r][c4 + j] = v[j] * gv;
    }
  }
  __syncthreads();
  {
    const int nq = t & 15, dr0 = t >> 4;
#pragma unroll
    for (int uu = 0; uu < 4; ++uu) {
      int d = dr0 + 16 * uu;
      h4 o;
#pragma unroll
      for (int j = 0; j < 4; ++j) o[j] = (_Float16)tile[nq * 4 + j][d];
      *(h4*)(xg16T + (size_t)(d0 + d) * N + n0 + nq * 4) = o;
    }
  }
}

// ---------------- K2: view2 partials = adj_sel @ xg via f16 MFMA, split-K plain stores ----
__global__ __launch_bounds__(256) void k2_mfma(
    const float* __restrict__ adj, const _Float16* __restrict__ xg16T,
    const int* __restrict__ rows_sel, const int* __restrict__ cnt,
    float* __restrict__ view2p, int N) {
  __shared__ __align__(16) unsigned short Ab[BM * BK];
  __shared__ __align__(16) unsigned short Bb[DD * BK];
  __shared__ int rloc[BM];
  const int Nc = *cnt;
  const int rbase = blockIdx.x * BM;
  if (rbase >= Nc) return;
  const int t = threadIdx.x;
  if (t < BM) {
    int m = rbase + t;
    rloc[t] = rows_sel[m < Nc ? m : Nc - 1];
  }
  __syncthreads();
  const int lane = t & 63, wave = t >> 6;
  const int li = lane & 15, g = lane >> 4;
  // A staging mapping: thread covers row am, 4 f4-quads
  const int am = t >> 2, asub = t & 3;
  const size_t arow = (size_t)rloc[am] * (size_t)N;
  const int aswz = (am & 7) << 4;
  // B staging mapping: thread covers row bd, one 64B half
  const int bd = t >> 1, bhalf = t & 1;
  const size_t brow = (size_t)bd * (size_t)N;
  const int bswz = (bd & 7) << 4;
  // fragment-read constants
  const int arbyte = (wave * 16 + li) * (BK * 2);
  const int fswz = (li & 7) << 4;

  f4 acc[8];
#pragma unroll
  for (int i = 0; i < 8; ++i) acc[i] = (f4){0.f, 0.f, 0.f, 0.f};

  const int kchunk = N / KSPLIT;
  const int kbeg = blockIdx.y * kchunk;

  for (int kt = 0; kt < kchunk; kt += BK) {
    const int k0 = kbeg + kt;
    __syncthreads();
    // ---- stage A: gathered adj rows, fp32 -> f16
#pragma unroll
    for (int i = 0; i < 4; ++i) {
      int q = asub + 4 * i;
      f4 v = *(const f4*)(adj + arow + (size_t)(k0 + q * 4));
      h4 hv;
      hv[0] = (_Float16)v[0];
      hv[1] = (_Float16)v[1];
      hv[2] = (_Float16)v[2];
      hv[3] = (_Float16)v[3];
      *(h4*)((char*)Ab + am * (BK * 2) + ((q * 8) ^ aswz)) = hv;
    }
    // ---- stage B: xg16T rows (already f16), straight 16B copies
#pragma unroll
    for (int i = 0; i < 4; ++i) {
      int boff = bhalf * 64 + i * 16;
      u32x4 v = *(const u32x4*)((const char*)xg16T + (brow + (size_t)k0) * 2 + boff);
      *(u32x4*)((char*)Bb + bd * (BK * 2) + (boff ^ bswz)) = v;
    }
    __syncthreads();
    // ---- compute: 2 k-steps of 16x16x32, 8 col-tiles each
#pragma unroll
    for (int s = 0; s < 2; ++s) {
      h8 af = *(const h8*)((const char*)Ab + arbyte + ((s * 64 + g * 16) ^ fswz));
#pragma unroll
      for (int c = 0; c < 8; ++c) {
        int br = c * 16 + li;
        h8 bf = *(const h8*)((const char*)Bb + br * (BK * 2) +
                             ((s * 64 + g * 16) ^ fswz));
        acc[c] = __builtin_amdgcn_mfma_f32_16x16x32_f16(af, bf, acc[c], 0, 0, 0);
      }
    }
  }
  // ---- epilogue: plain stores to split-K partial plane (no atomics, no zero-init)
  const size_t plane = (size_t)blockIdx.y * (size_t)N * DD;
#pragma unroll
  for (int c = 0; c < 8; ++c) {
#pragma unroll
    for (int r = 0; r < 4; ++r) {
      int mi = wave * 16 + g * 4 + r;
      if (rbase + mi < Nc)
        view2p[plane + (size_t)rloc[mi] * DD + c * 16 + li] = acc[c][r];
    }
  }
}

// ---------------- K3: sum partials + fusion gate + mix + residual LN ----------------
__global__ __launch_bounds__(256) void k3_epilogue(
    const float* __restrict__ x, const float* __restrict__ x_norm,
    const float* __restrict__ view2p, const float* __restrict__ gatef,
    const float* __restrict__ W1, const float* __restrict__ b1,
    const float* __restrict__ W2, const float* __restrict__ b2,
    const float* __restrict__ Wg, const float* __restrict__ bg,
    const float* __restrict__ g_out, const float* __restrict__ b_out,
    float* __restrict__ out, int N) {
  __shared__ float t1[K3R][DD];
  __shared__ float t2[K3R][DD];
  const int row0 = blockIdx.x * K3R;
  const int t = threadIdx.x;
  {
    const int cs = (t & 31) * 4, rs = t >> 5;
#pragma unroll
    for (int uu = 0; uu < 4; ++uu) {
      int r = rs + 8 * uu;
      int row = row0 + r;
      *(f4*)&t1[r][cs] = *(const f4*)(x_norm + (size_t)row * DD + cs);
      f4 sum = {0.f, 0.f, 0.f, 0.f};
      if (gatef[row] != 0.0f) {  // never-written partial rows stay unread (poison!)
#pragma unroll
        for (int ks = 0; ks < KSPLIT; ++ks)
          sum += *(const f4*)(view2p + ((size_t)ks * N + row) * DD + cs);
      }
      *(f4*)&t2[r][cs] = sum;
    }
  }
  __syncthreads();
  const int rg = t >> 5;
  const int cb = (t & 31) * 4;
  f4 zero = {0.f, 0.f, 0.f, 0.f};
  f4 fg4[4] = {zero, zero, zero, zero};
  f4 h14[4] = {zero, zero, zero, zero};
  f4 h24[4] = {zero, zero, zero, zero};
#pragma unroll 2
  for (int j = 0; j < DD; ++j) {
    f4 wg1 = *(const f4*)(Wg + j * DD + cb);
    f4 wg2 = *(const f4*)(Wg + (j + DD) * DD + cb);
    f4 w1 = *(const f4*)(W1 + j * DD + cb);
    f4 w2 = *(const f4*)(W2 + j * DD + cb);
#pragma unroll
    for (int rr = 0; rr < 4; ++rr) {
      float tv1 = t1[rg * 4 + rr][j];
      float tv2 = t2[rg * 4 + rr][j];
      fg4[rr] += tv1 * wg1 + tv2 * wg2;
      h14[rr] += tv1 * w1;
      h24[rr] += tv2 * w2;
    }
  }
  f4 bgv = *(const f4*)(bg + cb);
  f4 b1v = *(const f4*)(b1 + cb);
  f4 b2v = *(const f4*)(b2 + cb);
  f4 goutv = *(const f4*)(g_out + cb);
  f4 boutv = *(const f4*)(b_out + cb);
#pragma unroll
  for (int rr = 0; rr < 4; ++rr) {
    int row = row0 + rg * 4 + rr;
    f4 fg;
#pragma unroll
    for (int c = 0; c < 4; ++c)
      fg[c] = 1.0f / (1.0f + expf(-(fg4[rr][c] + bgv[c])));
    f4 h1 = h14[rr] + b1v;
    f4 h2 = h24[rr] + b2v;
    f4 fused = fg * h1 + (1.0f - fg) * h2;
    f4 xres = *(const f4*)(x + (size_t)row * DD + cb);
    f4 sres = fused + xres;
    float ps = sres[0] + sres[1] + sres[2] + sres[3];
#pragma unroll
    for (int off = 16; off; off >>= 1) ps += __shfl_xor(ps, off, 32);
    float mean = ps * (1.0f / 128.0f);
    f4 dx = sres - mean;
    float pq = dx[0] * dx[0] + dx[1] * dx[1] + dx[2] * dx[2] + dx[3] * dx[3];
#pragma unroll
    for (int off = 16; off; off >>= 1) pq += __shfl_xor(pq, off, 32);
    float inv = 1.0f / sqrtf(pq * (1.0f / 128.0f) + 1e-5f);
    f4 o = dx * inv * goutv + boutv;
    *(f4*)(out + (size_t)row * DD + cb) = o;
  }
}

extern "C" void kernel_launch(void* const* d_in, const int* in_sizes, int n_in,
                              void* d_out, int out_size, void* d_ws, size_t ws_size,
                              hipStream_t stream) {
  const float* x = (const float*)d_in[0];
  const float* adj = (const float*)d_in[1];
  const float* u = (const float*)d_in[2];
  const float* W1 = (const float*)d_in[3];
  const float* b1 = (const float*)d_in[4];
  const float* W2 = (const float*)d_in[5];
  const float* b2 = (const float*)d_in[6];
  const float* Wg = (const float*)d_in[7];
  const float* bg = (const float*)d_in[8];
  const float* Wn = (const float*)d_in[9];
  const float* bn = (const float*)d_in[10];
  const float* g_in = (const float*)d_in[11];
  const float* b_in = (const float*)d_in[12];
  const float* g_out = (const float*)d_in[13];
  const float* b_out = (const float*)d_in[14];
  float* out = (float*)d_out;

  const int N = in_sizes[2] / 2;  // 12288

  char* ws = (char*)d_ws;
  int* cnt = (int*)ws;                             // 4 B (pad to 256)
  int* rows_sel = (int*)(ws + 256);                // N*4
  size_t o_gate = 256 + (size_t)N * 4;
  float* gatef = (float*)(ws + o_gate);            // N*4
  size_t o_xn = o_gate + (size_t)N * 4;
  float* x_norm = (float*)(ws + o_xn);             // N*128*4
  size_t o_xt = o_xn + (size_t)N * DD * 4;
  _Float16* xg16T = (_Float16*)(ws + o_xt);        // 128*N*2
  size_t o_v2p = o_xt + (size_t)DD * N * 2;
  float* view2p = (float*)(ws + o_v2p);            // KSPLIT*N*128*4 (~50 MB)

  hipMemsetAsync(cnt, 0, 4, stream);

  k1_ln_gate<<<N / 4, 256, 0, stream>>>(x, u, Wn, bn, g_in, b_in, x_norm, gatef,
                                        rows_sel, cnt, N);
  k1b_transpose<<<dim3(N / 64, DD / 64), 256, 0, stream>>>(x_norm, gatef, xg16T, N);
  k2_mfma<<<dim3(N / BM, KSPLIT), 256, 0, stream>>>(adj, xg16T, rows_sel, cnt,
                                                    view2p, N);
  k3_epilogue<<<N / K3R, 256, 0, stream>>>(x, x_norm, view2p, gatef, W1, b1, W2,
                                           b2, Wg, bg, g_out, b_out, out, N);
}

// Round 3
// 897.586 us; speedup vs baseline: 1.0012x; 1.0012x over previous
//
#include <hip/hip_runtime.h>

#define DD 128
#define KSPLIT 16
#define BM 128
#define BK 64
#define K3R 32

typedef float f4 __attribute__((ext_vector_type(4)));
typedef _Float16 h4 __attribute__((ext_vector_type(4)));
typedef _Float16 h8 __attribute__((ext_vector_type(8)));
typedef unsigned int u32x4 __attribute__((ext_vector_type(4)));

// ---------------- K1: LayerNorm + gumbel gate + compaction ----------------
__global__ __launch_bounds__(256) void k1_ln_gate(
    const float* __restrict__ x, const float* __restrict__ u,
    const float* __restrict__ Wn, const float* __restrict__ bn,
    const float* __restrict__ g_in, const float* __restrict__ b_in,
    float* __restrict__ x_norm, float* __restrict__ gatef,
    int* __restrict__ rows_sel, int* __restrict__ cnt, int N) {
  int wave = threadIdx.x >> 6, lane = threadIdx.x & 63;
  int row = blockIdx.x * 4 + wave;
  if (row >= N) return;
  int d0 = lane, d1 = lane + 64;
  float x0 = x[(size_t)row * DD + d0];
  float x1 = x[(size_t)row * DD + d1];
  float s = x0 + x1;
#pragma unroll
  for (int off = 32; off; off >>= 1) s += __shfl_xor(s, off, 64);
  float mean = s * (1.0f / 128.0f);
  float dx0 = x0 - mean, dx1 = x1 - mean;
  float v = dx0 * dx0 + dx1 * dx1;
#pragma unroll
  for (int off = 32; off; off >>= 1) v += __shfl_xor(v, off, 64);
  float inv = 1.0f / sqrtf(v * (1.0f / 128.0f) + 1e-5f);
  float xn0 = dx0 * inv * g_in[d0] + b_in[d0];
  float xn1 = dx1 * inv * g_in[d1] + b_in[d1];
  x_norm[(size_t)row * DD + d0] = xn0;
  x_norm[(size_t)row * DD + d1] = xn1;
  float l0 = xn0 * Wn[2 * d0] + xn1 * Wn[2 * d1];
  float l1 = xn0 * Wn[2 * d0 + 1] + xn1 * Wn[2 * d1 + 1];
#pragma unroll
  for (int off = 32; off; off >>= 1) {
    l0 += __shfl_xor(l0, off, 64);
    l1 += __shfl_xor(l1, off, 64);
  }
  float u0 = u[2 * row], u1 = u[2 * row + 1];
  float g0 = -logf(-logf(fminf(fmaxf(u0, 1e-10f), 1.0f)) + 1e-10f);
  float g1 = -logf(-logf(fminf(fmaxf(u1, 1e-10f), 1.0f)) + 1e-10f);
  float z0 = l0 + bn[0] + g0;
  float z1 = l1 + bn[1] + g1;
  bool gate = (z1 > z0);
  if (lane == 0) {
    gatef[row] = gate ? 1.0f : 0.0f;
    if (gate) {
      int p = atomicAdd(cnt, 1);
      rows_sel[p] = row;
    }
  }
}

// ---------------- K1b: xg16T[d][n] = gate[n]*x_norm[n][d] in f16 (tiled transpose) ----
__global__ __launch_bounds__(256) void k1b_transpose(
    const float* __restrict__ x_norm, const float* __restrict__ gatef,
    _Float16* __restrict__ xg16T, int N) {
  __shared__ float tile[64][65];
  const int n0 = blockIdx.x * 64;
  const int d0 = blockIdx.y * 64;
  const int t = threadIdx.x;
  {
    const int c4 = (t & 15) * 4, r0 = t >> 4;
#pragma unroll
    for (int uu = 0; uu < 4; ++uu) {
      int r = r0 + 16 * uu;
      float gv = gatef[n0 + r];
      f4 v = *(const f4*)(x_norm + (size_t)(n0 + r) * DD + d0 + c4);
#pragma unroll
      for (int j = 0; j < 4; ++j) tile[r][c4 + j] = v[j] * gv;
    }
  }
  __syncthreads();
  {
    const int nq = t & 15, dr0 = t >> 4;
#pragma unroll
    for (int uu = 0; uu < 4; ++uu) {
      int d = dr0 + 16 * uu;
      h4 o;
#pragma unroll
      for (int j = 0; j < 4; ++j) o[j] = (_Float16)tile[nq * 4 + j][d];
      *(h4*)(xg16T + (size_t)(d0 + d) * N + n0 + nq * 4) = o;
    }
  }
}

// ---------------- K2: view2 partials = adj_sel @ xg, f16 MFMA, T14 reg-prefetch ----
// A tile [BM][BK] f16, B tile [DD][BK] f16, single-buffered LDS, 16B-XOR swizzle.
__global__ __launch_bounds__(256, 3) void k2_mfma(
    const float* __restrict__ adj, const _Float16* __restrict__ xg16T,
    const int* __restrict__ rows_sel, const int* __restrict__ cnt,
    float* __restrict__ view2p, int N) {
  __shared__ __align__(16) unsigned short Ab[BM * BK];  // 16 KB
  __shared__ __align__(16) unsigned short Bb[DD * BK];  // 16 KB
  __shared__ int rloc[BM];
  const int Nc = *cnt;
  const int rbase = blockIdx.x * BM;
  if (rbase >= Nc) return;
  const int t = threadIdx.x;
  if (t < BM) {
    int m = rbase + t;
    rloc[t] = rows_sel[m < Nc ? m : Nc - 1];
  }
  __syncthreads();
  const int lane = t & 63, wave = t >> 6;
  const int li = lane & 15, g = lane >> 4;
  // staging mapping: each thread owns half of one row (64B of the 128B f16 row)
  const int srow = t >> 1, shalf = t & 1;
  const size_t agbase = (size_t)rloc[srow] * (size_t)N + (size_t)(shalf * 32);
  const size_t bgrow = (size_t)srow * (size_t)N;
  const int sswz = (srow & 7) << 4;
  const int fswz = (li & 7) << 4;

  f4 acc0[8], acc1[8];
#pragma unroll
  for (int i = 0; i < 8; ++i) {
    acc0[i] = (f4){0.f, 0.f, 0.f, 0.f};
    acc1[i] = (f4){0.f, 0.f, 0.f, 0.f};
  }

  const int kchunk = N / KSPLIT;   // 768
  const int kbeg = blockIdx.y * kchunk;
  const int ntiles = kchunk / BK;  // 12

  f4 areg[8];
  u32x4 breg[4];
  // prologue: prefetch tile 0 into regs
  {
    const float* ap = adj + agbase + kbeg;
#pragma unroll
    for (int j = 0; j < 8; ++j) areg[j] = *(const f4*)(ap + j * 4);
    const char* bp = (const char*)xg16T + (bgrow + (size_t)kbeg) * 2 + shalf * 64;
#pragma unroll
    for (int i = 0; i < 4; ++i) breg[i] = *(const u32x4*)(bp + i * 16);
  }

  for (int kt = 0; kt < ntiles; ++kt) {
    __syncthreads();  // previous tile's LDS reads done
    // ---- write staged regs -> LDS (implicit vmcnt waits here only)
    {
      char* abase = (char*)Ab + srow * (BK * 2);
#pragma unroll
      for (int j2 = 0; j2 < 4; ++j2) {
        f4 v0 = areg[2 * j2], v1 = areg[2 * j2 + 1];
        h8 hv;
        hv[0] = (_Float16)v0[0]; hv[1] = (_Float16)v0[1];
        hv[2] = (_Float16)v0[2]; hv[3] = (_Float16)v0[3];
        hv[4] = (_Float16)v1[0]; hv[5] = (_Float16)v1[1];
        hv[6] = (_Float16)v1[2]; hv[7] = (_Float16)v1[3];
        *(h8*)(abase + ((shalf * 64 + j2 * 16) ^ sswz)) = hv;
      }
      char* bbase = (char*)Bb + srow * (BK * 2);
#pragma unroll
      for (int i = 0; i < 4; ++i)
        *(u32x4*)(bbase + ((shalf * 64 + i * 16) ^ sswz)) = breg[i];
    }
    __syncthreads();  // staging visible
    // ---- issue next tile's global loads (latency hides under compute)
    if (kt + 1 < ntiles) {
      const int k0 = kbeg + (kt + 1) * BK;
      const float* ap = adj + agbase + k0;
#pragma unroll
      for (int j = 0; j < 8; ++j) areg[j] = *(const f4*)(ap + j * 4);
      const char* bp = (const char*)xg16T + (bgrow + (size_t)k0) * 2 + shalf * 64;
#pragma unroll
      for (int i = 0; i < 4; ++i) breg[i] = *(const u32x4*)(bp + i * 16);
    }
    // ---- compute: 2 k-steps x (2 row-subtiles x 8 col-tiles)
#pragma unroll
    for (int s = 0; s < 2; ++s) {
      const int koff = (s * 64 + g * 16) ^ fswz;
      h8 af0 = *(const h8*)((const char*)Ab + (wave * 32 + li) * (BK * 2) + koff);
      h8 af1 = *(const h8*)((const char*)Ab + (wave * 32 + 16 + li) * (BK * 2) + koff);
#pragma unroll
      for (int c = 0; c < 8; ++c) {
        h8 bf = *(const h8*)((const char*)Bb + (c * 16 + li) * (BK * 2) + koff);
        acc0[c] = __builtin_amdgcn_mfma_f32_16x16x32_f16(af0, bf, acc0[c], 0, 0, 0);
        acc1[c] = __builtin_amdgcn_mfma_f32_16x16x32_f16(af1, bf, acc1[c], 0, 0, 0);
      }
    }
  }
  // ---- epilogue: plain stores to this y-block's partial plane
  const size_t plane = (size_t)blockIdx.y * (size_t)N * DD;
#pragma unroll
  for (int c = 0; c < 8; ++c) {
#pragma unroll
    for (int q = 0; q < 4; ++q) {
      int mi0 = wave * 32 + g * 4 + q;
      int mi1 = mi0 + 16;
      if (rbase + mi0 < Nc)
        view2p[plane + (size_t)rloc[mi0] * DD + c * 16 + li] = acc0[c][q];
      if (rbase + mi1 < Nc)
        view2p[plane + (size_t)rloc[mi1] * DD + c * 16 + li] = acc1[c][q];
    }
  }
}

// ---------------- K3: sum partials + fusion gate + mix + residual LN ----------------
__global__ __launch_bounds__(256) void k3_epilogue(
    const float* __restrict__ x, const float* __restrict__ x_norm,
    const float* __restrict__ view2p, const float* __restrict__ gatef,
    const float* __restrict__ W1, const float* __restrict__ b1,
    const float* __restrict__ W2, const float* __restrict__ b2,
    const float* __restrict__ Wg, const float* __restrict__ bg,
    const float* __restrict__ g_out, const float* __restrict__ b_out,
    float* __restrict__ out, int N) {
  __shared__ float t1[K3R][DD];
  __shared__ float t2[K3R][DD];
  const int row0 = blockIdx.x * K3R;
  const int t = threadIdx.x;
  {
    const int cs = (t & 31) * 4, rs = t >> 5;
#pragma unroll
    for (int uu = 0; uu < 4; ++uu) {
      int r = rs + 8 * uu;
      int row = row0 + r;
      *(f4*)&t1[r][cs] = *(const f4*)(x_norm + (size_t)row * DD + cs);
      f4 sum = {0.f, 0.f, 0.f, 0.f};
      if (gatef[row] != 0.0f) {  // never-written partial rows stay unread (poison!)
#pragma unroll
        for (int ks = 0; ks < KSPLIT; ++ks)
          sum += *(const f4*)(view2p + ((size_t)ks * N + row) * DD + cs);
      }
      *(f4*)&t2[r][cs] = sum;
    }
  }
  __syncthreads();
  const int rg = t >> 5;
  const int cb = (t & 31) * 4;
  f4 zero = {0.f, 0.f, 0.f, 0.f};
  f4 fg4[4] = {zero, zero, zero, zero};
  f4 h14[4] = {zero, zero, zero, zero};
  f4 h24[4] = {zero, zero, zero, zero};
#pragma unroll 2
  for (int j = 0; j < DD; ++j) {
    f4 wg1 = *(const f4*)(Wg + j * DD + cb);
    f4 wg2 = *(const f4*)(Wg + (j + DD) * DD + cb);
    f4 w1 = *(const f4*)(W1 + j * DD + cb);
    f4 w2 = *(const f4*)(W2 + j * DD + cb);
#pragma unroll
    for (int rr = 0; rr < 4; ++rr) {
      float tv1 = t1[rg * 4 + rr][j];
      float tv2 = t2[rg * 4 + rr][j];
      fg4[rr] += tv1 * wg1 + tv2 * wg2;
      h14[rr] += tv1 * w1;
      h24[rr] += tv2 * w2;
    }
  }
  f4 bgv = *(const f4*)(bg + cb);
  f4 b1v = *(const f4*)(b1 + cb);
  f4 b2v = *(const f4*)(b2 + cb);
  f4 goutv = *(const f4*)(g_out + cb);
  f4 boutv = *(const f4*)(b_out + cb);
#pragma unroll
  for (int rr = 0; rr < 4; ++rr) {
    int row = row0 + rg * 4 + rr;
    f4 fg;
#pragma unroll
    for (int c = 0; c < 4; ++c)
      fg[c] = 1.0f / (1.0f + expf(-(fg4[rr][c] + bgv[c])));
    f4 h1 = h14[rr] + b1v;
    f4 h2 = h24[rr] + b2v;
    f4 fused = fg * h1 + (1.0f - fg) * h2;
    f4 xres = *(const f4*)(x + (size_t)row * DD + cb);
    f4 sres = fused + xres;
    float ps = sres[0] + sres[1] + sres[2] + sres[3];
#pragma unroll
    for (int off = 16; off; off >>= 1) ps += __shfl_xor(ps, off, 32);
    float mean = ps * (1.0f / 128.0f);
    f4 dx = sres - mean;
    float pq = dx[0] * dx[0] + dx[1] * dx[1] + dx[2] * dx[2] + dx[3] * dx[3];
#pragma unroll
    for (int off = 16; off; off >>= 1) pq += __shfl_xor(pq, off, 32);
    float inv = 1.0f / sqrtf(pq * (1.0f / 128.0f) + 1e-5f);
    f4 o = dx * inv * goutv + boutv;
    *(f4*)(out + (size_t)row * DD + cb) = o;
  }
}

extern "C" void kernel_launch(void* const* d_in, const int* in_sizes, int n_in,
                              void* d_out, int out_size, void* d_ws, size_t ws_size,
                              hipStream_t stream) {
  const float* x = (const float*)d_in[0];
  const float* adj = (const float*)d_in[1];
  const float* u = (const float*)d_in[2];
  const float* W1 = (const float*)d_in[3];
  const float* b1 = (const float*)d_in[4];
  const float* W2 = (const float*)d_in[5];
  const float* b2 = (const float*)d_in[6];
  const float* Wg = (const float*)d_in[7];
  const float* bg = (const float*)d_in[8];
  const float* Wn = (const float*)d_in[9];
  const float* bn = (const float*)d_in[10];
  const float* g_in = (const float*)d_in[11];
  const float* b_in = (const float*)d_in[12];
  const float* g_out = (const float*)d_in[13];
  const float* b_out = (const float*)d_in[14];
  float* out = (float*)d_out;

  const int N = in_sizes[2] / 2;  // 12288

  char* ws = (char*)d_ws;
  int* cnt = (int*)ws;                             // 4 B (pad to 256)
  int* rows_sel = (int*)(ws + 256);                // N*4
  size_t o_gate = 256 + (size_t)N * 4;
  float* gatef = (float*)(ws + o_gate);            // N*4
  size_t o_xn = o_gate + (size_t)N * 4;
  float* x_norm = (float*)(ws + o_xn);             // N*128*4
  size_t o_xt = o_xn + (size_t)N * DD * 4;
  _Float16* xg16T = (_Float16*)(ws + o_xt);        // 128*N*2
  size_t o_v2p = o_xt + (size_t)DD * N * 2;
  float* view2p = (float*)(ws + o_v2p);            // KSPLIT*N*128*4 (~100 MB)

  hipMemsetAsync(cnt, 0, 4, stream);

  k1_ln_gate<<<N / 4, 256, 0, stream>>>(x, u, Wn, bn, g_in, b_in, x_norm, gatef,
                                        rows_sel, cnt, N);
  k1b_transpose<<<dim3(N / 64, DD / 64), 256, 0, stream>>>(x_norm, gatef, xg16T, N);
  k2_mfma<<<dim3(N / BM, KSPLIT), 256, 0, stream>>>(adj, xg16T, rows_sel, cnt,
                                                    view2p, N);
  k3_epilogue<<<N / K3R, 256, 0, stream>>>(x, x_norm, view2p, gatef, W1, b1, W2,
                                           b2, Wg, bg, g_out, b_out, out, N);
}